// Round 1
// baseline (318.774 us; speedup 1.0000x reference)
//
#include <hip/hip_runtime.h>
#include <math.h>

// ---------------- setup kernels: degree, rsqrt, scan, CSR fill ----------------

__global__ void count_kernel(const int* __restrict__ row, int* __restrict__ cnt, int E) {
    int e = blockIdx.x * 256 + threadIdx.x;
    if (e < E) atomicAdd(&cnt[row[e]], 1);
}

__global__ void dis_kernel(const int* __restrict__ cnt, float* __restrict__ dis, int N) {
    int i = blockIdx.x * 256 + threadIdx.x;
    if (i < N) dis[i] = rsqrtf((float)cnt[i] + 1.0f);   // +1 self loop, deg>=1 always
}

// exclusive scan of cnt[N] -> offs[N]; per-block (1024 elems) + block sums
__global__ void scan1_kernel(const int* __restrict__ cnt, int* __restrict__ excl,
                             int* __restrict__ blksum, int N) {
    __shared__ int sdata[256];
    int t = threadIdx.x;
    int base = blockIdx.x * 1024 + t * 4;
    int v0 = (base + 0 < N) ? cnt[base + 0] : 0;
    int v1 = (base + 1 < N) ? cnt[base + 1] : 0;
    int v2 = (base + 2 < N) ? cnt[base + 2] : 0;
    int v3 = (base + 3 < N) ? cnt[base + 3] : 0;
    int tot = v0 + v1 + v2 + v3;
    sdata[t] = tot;
    __syncthreads();
    for (int o = 1; o < 256; o <<= 1) {
        int x = (t >= o) ? sdata[t - o] : 0;
        __syncthreads();
        sdata[t] += x;
        __syncthreads();
    }
    int incl = sdata[t];
    int eb = incl - tot;
    if (base + 0 < N) excl[base + 0] = eb;
    if (base + 1 < N) excl[base + 1] = eb + v0;
    if (base + 2 < N) excl[base + 2] = eb + v0 + v1;
    if (base + 3 < N) excl[base + 3] = eb + v0 + v1 + v2;
    if (t == 255) blksum[blockIdx.x] = incl;
}

__global__ void scan2_kernel(int* __restrict__ blksum, int nb) {  // 1 block, 64 threads
    int lane = threadIdx.x;
    int orig = (lane < nb) ? blksum[lane] : 0;
    int v = orig;
    for (int o = 1; o < 64; o <<= 1) { int x = __shfl_up(v, o); if (lane >= o) v += x; }
    if (lane < nb) blksum[lane] = v - orig;   // exclusive block base
}

__global__ void scan3_kernel(int* __restrict__ excl, const int* __restrict__ blksum,
                             int N, int E) {
    int i = blockIdx.x * 256 + threadIdx.x;
    if (i < N) excl[i] += blksum[i >> 10];
    if (i == 0) excl[N] = E;
}

__global__ void fill_kernel(const int* __restrict__ ei, int E,
                            const int* __restrict__ offset, int* __restrict__ cursor,
                            const float* __restrict__ dis,
                            int* __restrict__ csr_col, float* __restrict__ csr_w) {
    int e = blockIdx.x * 256 + threadIdx.x;
    if (e >= E) return;
    int r = ei[e];          // destination
    int c = ei[E + e];      // source
    int pos = offset[r] + atomicAdd(&cursor[r], 1);
    csr_col[pos] = c;
    csr_w[pos] = dis[r] * dis[c];
}

// ---------------- GEMM: out[N][128] = A[N][128] @ W[128][128] ----------------

__global__ __launch_bounds__(256) void gemm_nk128(const float* __restrict__ A,
                                                  const float* __restrict__ W,
                                                  float* __restrict__ out, int N) {
    __shared__ float sA[32][64];     // A-tile transposed: sA[k][r]
    __shared__ float sW[32][128];
    const int t = threadIdx.x;
    const int tc = t & 15, tr = t >> 4;
    const int brow = blockIdx.x * 64;
    float acc[4][8];
#pragma unroll
    for (int r = 0; r < 4; ++r)
#pragma unroll
        for (int c = 0; c < 8; ++c) acc[r][c] = 0.0f;

    for (int kt = 0; kt < 128; kt += 32) {
#pragma unroll
        for (int i = 0; i < 2; ++i) {
            int idx = t + i * 256;          // 0..511
            int r = idx & 63, kq = idx >> 6;   // kq 0..7 -> k = kq*4
            int g = brow + r;
            float4 v = make_float4(0.f, 0.f, 0.f, 0.f);
            if (g < N) v = *(const float4*)&A[(size_t)g * 128 + kt + kq * 4];
            sA[kq * 4 + 0][r] = v.x; sA[kq * 4 + 1][r] = v.y;
            sA[kq * 4 + 2][r] = v.z; sA[kq * 4 + 3][r] = v.w;
        }
#pragma unroll
        for (int i = 0; i < 4; ++i) {
            int idx = t + i * 256;          // 0..1023
            int k = idx >> 5, cq = idx & 31;
            *(float4*)&sW[k][cq * 4] = *(const float4*)&W[(size_t)(kt + k) * 128 + cq * 4];
        }
        __syncthreads();
#pragma unroll
        for (int k = 0; k < 32; ++k) {
            float4 a  = *(const float4*)&sA[k][tr * 4];
            float4 b0 = *(const float4*)&sW[k][tc * 4];
            float4 b1 = *(const float4*)&sW[k][tc * 4 + 64];
            float ar[4] = {a.x, a.y, a.z, a.w};
            float bc[8] = {b0.x, b0.y, b0.z, b0.w, b1.x, b1.y, b1.z, b1.w};
#pragma unroll
            for (int r = 0; r < 4; ++r)
#pragma unroll
                for (int c = 0; c < 8; ++c)
                    acc[r][c] = fmaf(ar[r], bc[c], acc[r][c]);
        }
        __syncthreads();
    }
#pragma unroll
    for (int r = 0; r < 4; ++r) {
        int g = brow + tr * 4 + r;
        if (g < N) {
            float4 o0 = make_float4(acc[r][0], acc[r][1], acc[r][2], acc[r][3]);
            float4 o1 = make_float4(acc[r][4], acc[r][5], acc[r][6], acc[r][7]);
            *(float4*)&out[(size_t)g * 128 + tc * 4] = o0;
            *(float4*)&out[(size_t)g * 128 + tc * 4 + 64] = o1;
        }
    }
}

// ---------------- GEMM: out[N][16] = A[N][128] @ W[128][16] ----------------

__global__ __launch_bounds__(256) void gemm_nk16(const float* __restrict__ A,
                                                 const float* __restrict__ W,
                                                 float* __restrict__ out, int N) {
    __shared__ float sW[128][16];    // 8 KB
    __shared__ float sA[32][132];    // padded, 16.5 KB
    int t = threadIdx.x;
#pragma unroll
    for (int i = 0; i < 2; ++i) {
        int idx = t + i * 256;       // 0..511 float4s over 2048 floats
        *(float4*)&sW[idx >> 2][(idx & 3) * 4] = *(const float4*)&W[idx * 4];
    }
    int brow = blockIdx.x * 32;
#pragma unroll
    for (int i = 0; i < 4; ++i) {
        int idx = t + i * 256;       // 0..1023
        int rr = idx >> 5, cq = idx & 31;
        int g = brow + rr;
        float4 v = make_float4(0.f, 0.f, 0.f, 0.f);
        if (g < N) v = *(const float4*)&A[(size_t)g * 128 + cq * 4];
        *(float4*)&sA[rr][cq * 4] = v;
    }
    __syncthreads();
    int r = t >> 3;       // 0..31
    int cg = t & 7;       // cols cg*2, cg*2+1
    float a0 = 0.f, a1 = 0.f;
#pragma unroll
    for (int k = 0; k < 128; ++k) {
        float a = sA[r][k];
        float2 w = *(const float2*)&sW[k][cg * 2];
        a0 = fmaf(a, w.x, a0);
        a1 = fmaf(a, w.y, a1);
    }
    int g = brow + r;
    if (g < N) {
        out[(size_t)g * 16 + cg * 2 + 0] = a0;
        out[(size_t)g * 16 + cg * 2 + 1] = a1;
    }
}

// ------------- aggregation (128 wide): one wave per node, gather-only -------------

__global__ __launch_bounds__(256) void agg128_kernel(const float* __restrict__ t,
        const int* __restrict__ csr_col, const float* __restrict__ csr_w,
        const int* __restrict__ offset, const float* __restrict__ dis,
        const float* __restrict__ bias, float* __restrict__ out, int N, int do_relu) {
    int node = (blockIdx.x * 256 + threadIdx.x) >> 6;
    int lane = threadIdx.x & 63;
    if (node >= N) return;
    float d = dis[node];
    float sw = d * d;                         // self-loop weight 1/deg
    float2 acc = *(const float2*)&t[(size_t)node * 128 + lane * 2];
    acc.x *= sw; acc.y *= sw;
    int s = offset[node], e = offset[node + 1];
    int j = s;
    for (; j + 4 <= e; j += 4) {
        int c0 = csr_col[j], c1 = csr_col[j + 1], c2 = csr_col[j + 2], c3 = csr_col[j + 3];
        float w0 = csr_w[j], w1 = csr_w[j + 1], w2 = csr_w[j + 2], w3 = csr_w[j + 3];
        float2 v0 = *(const float2*)&t[(size_t)c0 * 128 + lane * 2];
        float2 v1 = *(const float2*)&t[(size_t)c1 * 128 + lane * 2];
        float2 v2 = *(const float2*)&t[(size_t)c2 * 128 + lane * 2];
        float2 v3 = *(const float2*)&t[(size_t)c3 * 128 + lane * 2];
        acc.x = fmaf(w0, v0.x, acc.x); acc.y = fmaf(w0, v0.y, acc.y);
        acc.x = fmaf(w1, v1.x, acc.x); acc.y = fmaf(w1, v1.y, acc.y);
        acc.x = fmaf(w2, v2.x, acc.x); acc.y = fmaf(w2, v2.y, acc.y);
        acc.x = fmaf(w3, v3.x, acc.x); acc.y = fmaf(w3, v3.y, acc.y);
    }
    for (; j < e; ++j) {
        int c = csr_col[j];
        float w = csr_w[j];
        float2 v = *(const float2*)&t[(size_t)c * 128 + lane * 2];
        acc.x = fmaf(w, v.x, acc.x); acc.y = fmaf(w, v.y, acc.y);
    }
    float2 b = *(const float2*)&bias[lane * 2];
    float ox = acc.x + b.x, oy = acc.y + b.y;
    if (do_relu) { ox = fmaxf(ox, 0.f); oy = fmaxf(oy, 0.f); }
    *(float2*)&out[(size_t)node * 128 + lane * 2] = make_float2(ox, oy);
}

// ------- aggregation (16 wide) + bias + log_softmax: 16 lanes per node -------

__global__ __launch_bounds__(256) void agg16_ls_kernel(const float* __restrict__ t2,
        const int* __restrict__ csr_col, const float* __restrict__ csr_w,
        const int* __restrict__ offset, const float* __restrict__ dis,
        const float* __restrict__ b2, float* __restrict__ out, int N) {
    int gid = blockIdx.x * 256 + threadIdx.x;
    int node = gid >> 4;
    int c = gid & 15;
    if (node >= N) return;
    float d = dis[node];
    float acc = d * d * t2[(size_t)node * 16 + c];
    int s = offset[node], e = offset[node + 1];
    for (int j = s; j < e; ++j) {
        int col = csr_col[j];
        float w = csr_w[j];
        acc = fmaf(w, t2[(size_t)col * 16 + c], acc);
    }
    float v = acc + b2[c];
    float m = v;
#pragma unroll
    for (int o = 1; o < 16; o <<= 1) m = fmaxf(m, __shfl_xor(m, o, 16));
    float ex = expf(v - m);
    float ssum = ex;
#pragma unroll
    for (int o = 1; o < 16; o <<= 1) ssum += __shfl_xor(ssum, o, 16);
    out[(size_t)node * 16 + c] = v - m - logf(ssum);
}

// ---------------------------------- launch ----------------------------------

extern "C" void kernel_launch(void* const* d_in, const int* in_sizes, int n_in,
                              void* d_out, int out_size, void* d_ws, size_t ws_size,
                              hipStream_t stream) {
    const float* x  = (const float*)d_in[0];
    const int*   ei = (const int*)d_in[1];
    const float* W0 = (const float*)d_in[2];
    const float* b0 = (const float*)d_in[3];
    const float* W1 = (const float*)d_in[4];
    const float* b1 = (const float*)d_in[5];
    const float* W2 = (const float*)d_in[6];
    const float* b2 = (const float*)d_in[7];
    int N = in_sizes[0] / 128;
    int E = in_sizes[1] / 2;
    float* out = (float*)d_out;

    char* ws = (char*)d_ws;
    size_t off = 0;
    auto alloc = [&](size_t bytes) -> void* {
        void* p = ws + off;
        off = (off + bytes + 255) & ~(size_t)255;
        return p;
    };
    float* tA      = (float*)alloc((size_t)N * 128 * 4);
    float* tB      = (float*)alloc((size_t)N * 128 * 4);
    float* t2      = (float*)alloc((size_t)N * 16 * 4);
    int*   cnt     = (int*)alloc((size_t)N * 4);
    int*   offs    = (int*)alloc((size_t)(N + 1) * 4);
    int*   cursor  = (int*)alloc((size_t)N * 4);
    int*   blksum  = (int*)alloc(64 * 4);
    float* dis     = (float*)alloc((size_t)N * 4);
    int*   csr_col = (int*)alloc((size_t)E * 4);
    float* csr_w   = (float*)alloc((size_t)E * 4);

    hipMemsetAsync(cnt, 0, (size_t)N * 4, stream);
    hipMemsetAsync(cursor, 0, (size_t)N * 4, stream);

    int nb = (N + 1023) / 1024;   // 49 for N=50000 (must be <= 64)
    count_kernel<<<(E + 255) / 256, 256, 0, stream>>>(ei, cnt, E);
    dis_kernel<<<(N + 255) / 256, 256, 0, stream>>>(cnt, dis, N);
    scan1_kernel<<<nb, 256, 0, stream>>>(cnt, offs, blksum, N);
    scan2_kernel<<<1, 64, 0, stream>>>(blksum, nb);
    scan3_kernel<<<(N + 255) / 256, 256, 0, stream>>>(offs, blksum, N, E);
    fill_kernel<<<(E + 255) / 256, 256, 0, stream>>>(ei, E, offs, cursor, dis, csr_col, csr_w);

    int gemm_blocks = (N + 63) / 64;
    int agg_blocks  = (int)(((size_t)N * 64 + 255) / 256);

    gemm_nk128<<<gemm_blocks, 256, 0, stream>>>(x, W0, tA, N);
    agg128_kernel<<<agg_blocks, 256, 0, stream>>>(tA, csr_col, csr_w, offs, dis, b0, tB, N, 1);
    gemm_nk128<<<gemm_blocks, 256, 0, stream>>>(tB, W1, tA, N);
    agg128_kernel<<<agg_blocks, 256, 0, stream>>>(tA, csr_col, csr_w, offs, dis, b1, tB, N, 1);
    gemm_nk16<<<(N + 31) / 32, 256, 0, stream>>>(tB, W2, t2, N);
    agg16_ls_kernel<<<(int)(((size_t)N * 16 + 255) / 256), 256, 0, stream>>>(
        t2, csr_col, csr_w, offs, dis, b2, out, N);
}

// Round 2
// 312.827 us; speedup vs baseline: 1.0190x; 1.0190x over previous
//
#include <hip/hip_runtime.h>
#include <math.h>

// ---------------- setup kernels: degree, rsqrt, scan, CSR fill ----------------

__global__ void count_kernel(const int* __restrict__ row, int* __restrict__ cnt, int E) {
    int e = blockIdx.x * 256 + threadIdx.x;
    if (e < E) atomicAdd(&cnt[row[e]], 1);
}

__global__ void dis_kernel(const int* __restrict__ cnt, float* __restrict__ dis, int N) {
    int i = blockIdx.x * 256 + threadIdx.x;
    if (i < N) dis[i] = rsqrtf((float)cnt[i] + 1.0f);   // +1 self loop, deg>=1 always
}

// exclusive scan of cnt[N] -> offs[N]; per-block (1024 elems) + block sums
__global__ void scan1_kernel(const int* __restrict__ cnt, int* __restrict__ excl,
                             int* __restrict__ blksum, int N) {
    __shared__ int sdata[256];
    int t = threadIdx.x;
    int base = blockIdx.x * 1024 + t * 4;
    int v0 = (base + 0 < N) ? cnt[base + 0] : 0;
    int v1 = (base + 1 < N) ? cnt[base + 1] : 0;
    int v2 = (base + 2 < N) ? cnt[base + 2] : 0;
    int v3 = (base + 3 < N) ? cnt[base + 3] : 0;
    int tot = v0 + v1 + v2 + v3;
    sdata[t] = tot;
    __syncthreads();
    for (int o = 1; o < 256; o <<= 1) {
        int x = (t >= o) ? sdata[t - o] : 0;
        __syncthreads();
        sdata[t] += x;
        __syncthreads();
    }
    int incl = sdata[t];
    int eb = incl - tot;
    if (base + 0 < N) excl[base + 0] = eb;
    if (base + 1 < N) excl[base + 1] = eb + v0;
    if (base + 2 < N) excl[base + 2] = eb + v0 + v1;
    if (base + 3 < N) excl[base + 3] = eb + v0 + v1 + v2;
    if (t == 255) blksum[blockIdx.x] = incl;
}

__global__ void scan2_kernel(int* __restrict__ blksum, int nb) {  // 1 block, 64 threads
    int lane = threadIdx.x;
    int orig = (lane < nb) ? blksum[lane] : 0;
    int v = orig;
    for (int o = 1; o < 64; o <<= 1) { int x = __shfl_up(v, o); if (lane >= o) v += x; }
    if (lane < nb) blksum[lane] = v - orig;   // exclusive block base
}

__global__ void scan3_kernel(int* __restrict__ excl, int* __restrict__ cursor,
                             const int* __restrict__ blksum, int N, int E) {
    int i = blockIdx.x * 256 + threadIdx.x;
    if (i < N) {
        int v = excl[i] + blksum[i >> 10];
        excl[i] = v;
        cursor[i] = v;      // cursor starts at row offset -> fill atomic gives abs pos
    }
    if (i == 0) excl[N] = E;
}

__global__ void fill_kernel(const int* __restrict__ ei, int E,
                            int* __restrict__ cursor, int* __restrict__ csr_col) {
    int e = blockIdx.x * 256 + threadIdx.x;
    if (e >= E) return;
    int r = ei[e];          // destination
    int c = ei[E + e];      // source
    int pos = atomicAdd(&cursor[r], 1);
    csr_col[pos] = c;
}

// ---------------- GEMM: out[N][128] = A[N][128] @ W[128][128] ----------------

__global__ __launch_bounds__(256) void gemm_nk128(const float* __restrict__ A,
                                                  const float* __restrict__ W,
                                                  float* __restrict__ out, int N) {
    __shared__ float sA[32][64];     // A-tile transposed: sA[k][r]
    __shared__ float sW[32][128];
    const int t = threadIdx.x;
    const int tc = t & 15, tr = t >> 4;
    const int brow = blockIdx.x * 64;
    float acc[4][8];
#pragma unroll
    for (int r = 0; r < 4; ++r)
#pragma unroll
        for (int c = 0; c < 8; ++c) acc[r][c] = 0.0f;

    for (int kt = 0; kt < 128; kt += 32) {
#pragma unroll
        for (int i = 0; i < 2; ++i) {
            int idx = t + i * 256;          // 0..511
            int r = idx & 63, kq = idx >> 6;   // kq 0..7 -> k = kq*4
            int g = brow + r;
            float4 v = make_float4(0.f, 0.f, 0.f, 0.f);
            if (g < N) v = *(const float4*)&A[(size_t)g * 128 + kt + kq * 4];
            sA[kq * 4 + 0][r] = v.x; sA[kq * 4 + 1][r] = v.y;
            sA[kq * 4 + 2][r] = v.z; sA[kq * 4 + 3][r] = v.w;
        }
#pragma unroll
        for (int i = 0; i < 4; ++i) {
            int idx = t + i * 256;          // 0..1023
            int k = idx >> 5, cq = idx & 31;
            *(float4*)&sW[k][cq * 4] = *(const float4*)&W[(size_t)(kt + k) * 128 + cq * 4];
        }
        __syncthreads();
#pragma unroll
        for (int k = 0; k < 32; ++k) {
            float4 a  = *(const float4*)&sA[k][tr * 4];
            float4 b0 = *(const float4*)&sW[k][tc * 4];
            float4 b1 = *(const float4*)&sW[k][tc * 4 + 64];
            float ar[4] = {a.x, a.y, a.z, a.w};
            float bc[8] = {b0.x, b0.y, b0.z, b0.w, b1.x, b1.y, b1.z, b1.w};
#pragma unroll
            for (int r = 0; r < 4; ++r)
#pragma unroll
                for (int c = 0; c < 8; ++c)
                    acc[r][c] = fmaf(ar[r], bc[c], acc[r][c]);
        }
        __syncthreads();
    }
#pragma unroll
    for (int r = 0; r < 4; ++r) {
        int g = brow + tr * 4 + r;
        if (g < N) {
            float4 o0 = make_float4(acc[r][0], acc[r][1], acc[r][2], acc[r][3]);
            float4 o1 = make_float4(acc[r][4], acc[r][5], acc[r][6], acc[r][7]);
            *(float4*)&out[(size_t)g * 128 + tc * 4] = o0;
            *(float4*)&out[(size_t)g * 128 + tc * 4 + 64] = o1;
        }
    }
}

// ---------------- GEMM: out[N][16] = A[N][128] @ W[128][16] ----------------

__global__ __launch_bounds__(256) void gemm_nk16(const float* __restrict__ A,
                                                 const float* __restrict__ W,
                                                 float* __restrict__ out, int N) {
    __shared__ float sW[128][16];    // 8 KB
    __shared__ float sA[32][132];    // padded, 16.5 KB
    int t = threadIdx.x;
#pragma unroll
    for (int i = 0; i < 2; ++i) {
        int idx = t + i * 256;       // 0..511 float4s over 2048 floats
        *(float4*)&sW[idx >> 2][(idx & 3) * 4] = *(const float4*)&W[idx * 4];
    }
    int brow = blockIdx.x * 32;
#pragma unroll
    for (int i = 0; i < 4; ++i) {
        int idx = t + i * 256;       // 0..1023
        int rr = idx >> 5, cq = idx & 31;
        int g = brow + rr;
        float4 v = make_float4(0.f, 0.f, 0.f, 0.f);
        if (g < N) v = *(const float4*)&A[(size_t)g * 128 + cq * 4];
        *(float4*)&sA[rr][cq * 4] = v;
    }
    __syncthreads();
    int r = t >> 3;       // 0..31
    int cg = t & 7;       // cols cg*2, cg*2+1
    float a0 = 0.f, a1 = 0.f;
#pragma unroll
    for (int k = 0; k < 128; ++k) {
        float a = sA[r][k];
        float2 w = *(const float2*)&sW[k][cg * 2];
        a0 = fmaf(a, w.x, a0);
        a1 = fmaf(a, w.y, a1);
    }
    int g = brow + r;
    if (g < N) {
        out[(size_t)g * 16 + cg * 2 + 0] = a0;
        out[(size_t)g * 16 + cg * 2 + 1] = a1;
    }
}

// ------------- aggregation (128 wide): one node per wave, 2 edges per VMEM -------------
// Wave split into two 32-lane halves; each half gathers a different edge's full
// 512B row via dwordx4. Cross-half combine with shfl_xor(...,32) at the end.

__global__ __launch_bounds__(256) void agg128_kernel(const float* __restrict__ t,
        const int* __restrict__ csr_col,
        const int* __restrict__ offset, const float* __restrict__ dis,
        const float* __restrict__ bias, float* __restrict__ out, int N, int do_relu) {
    int node = blockIdx.x * 4 + (threadIdx.x >> 6);
    if (node >= N) return;
    int lane = threadIdx.x & 63;
    int half = lane >> 5;
    int col4 = (lane & 31) * 4;          // float index of this lane's 4 columns
    float dn = dis[node];

    // self loop (weight dn^2), accumulated by half 0 only
    float4 self = *(const float4*)&t[(size_t)node * 128 + col4];
    float sw = half ? 0.0f : dn * dn;
    float4 acc;
    acc.x = sw * self.x; acc.y = sw * self.y; acc.z = sw * self.z; acc.w = sw * self.w;

    int s = offset[node], e = offset[node + 1];
    int j = s + half;                    // half 0: s, s+2, ... ; half 1: s+1, s+3, ...
    // 4 gathers (8 edges per wave) in flight
    for (; j + 6 < e; j += 8) {
        int c0 = csr_col[j];
        int c1 = csr_col[j + 2];
        int c2 = csr_col[j + 4];
        int c3 = csr_col[j + 6];
        float4 v0 = *(const float4*)&t[(size_t)c0 * 128 + col4];
        float4 v1 = *(const float4*)&t[(size_t)c1 * 128 + col4];
        float4 v2 = *(const float4*)&t[(size_t)c2 * 128 + col4];
        float4 v3 = *(const float4*)&t[(size_t)c3 * 128 + col4];
        float w0 = dn * dis[c0];
        float w1 = dn * dis[c1];
        float w2 = dn * dis[c2];
        float w3 = dn * dis[c3];
        acc.x = fmaf(w0, v0.x, acc.x); acc.y = fmaf(w0, v0.y, acc.y);
        acc.z = fmaf(w0, v0.z, acc.z); acc.w = fmaf(w0, v0.w, acc.w);
        acc.x = fmaf(w1, v1.x, acc.x); acc.y = fmaf(w1, v1.y, acc.y);
        acc.z = fmaf(w1, v1.z, acc.z); acc.w = fmaf(w1, v1.w, acc.w);
        acc.x = fmaf(w2, v2.x, acc.x); acc.y = fmaf(w2, v2.y, acc.y);
        acc.z = fmaf(w2, v2.z, acc.z); acc.w = fmaf(w2, v2.w, acc.w);
        acc.x = fmaf(w3, v3.x, acc.x); acc.y = fmaf(w3, v3.y, acc.y);
        acc.z = fmaf(w3, v3.z, acc.z); acc.w = fmaf(w3, v3.w, acc.w);
    }
    for (; j < e; j += 2) {
        int c = csr_col[j];
        float4 v = *(const float4*)&t[(size_t)c * 128 + col4];
        float w = dn * dis[c];
        acc.x = fmaf(w, v.x, acc.x); acc.y = fmaf(w, v.y, acc.y);
        acc.z = fmaf(w, v.z, acc.z); acc.w = fmaf(w, v.w, acc.w);
    }
    // combine the two halves
    acc.x += __shfl_xor(acc.x, 32);
    acc.y += __shfl_xor(acc.y, 32);
    acc.z += __shfl_xor(acc.z, 32);
    acc.w += __shfl_xor(acc.w, 32);
    if (half == 0) {
        float4 b = *(const float4*)&bias[col4];
        float4 o;
        o.x = acc.x + b.x; o.y = acc.y + b.y; o.z = acc.z + b.z; o.w = acc.w + b.w;
        if (do_relu) {
            o.x = fmaxf(o.x, 0.f); o.y = fmaxf(o.y, 0.f);
            o.z = fmaxf(o.z, 0.f); o.w = fmaxf(o.w, 0.f);
        }
        *(float4*)&out[(size_t)node * 128 + col4] = o;
    }
}

// ------- aggregation (16 wide) + bias + log_softmax: 16 lanes per node -------

__global__ __launch_bounds__(256) void agg16_ls_kernel(const float* __restrict__ t2,
        const int* __restrict__ csr_col,
        const int* __restrict__ offset, const float* __restrict__ dis,
        const float* __restrict__ b2, float* __restrict__ out, int N) {
    int gid = blockIdx.x * 256 + threadIdx.x;
    int node = gid >> 4;
    int c = gid & 15;
    if (node >= N) return;
    float dn = dis[node];
    float acc = dn * dn * t2[(size_t)node * 16 + c];
    int s = offset[node], e = offset[node + 1];
    for (int j = s; j < e; ++j) {
        int col = csr_col[j];
        float w = dn * dis[col];
        acc = fmaf(w, t2[(size_t)col * 16 + c], acc);
    }
    float v = acc + b2[c];
    float m = v;
#pragma unroll
    for (int o = 1; o < 16; o <<= 1) m = fmaxf(m, __shfl_xor(m, o, 16));
    float ex = expf(v - m);
    float ssum = ex;
#pragma unroll
    for (int o = 1; o < 16; o <<= 1) ssum += __shfl_xor(ssum, o, 16);
    out[(size_t)node * 16 + c] = v - m - logf(ssum);
}

// ---------------------------------- launch ----------------------------------

extern "C" void kernel_launch(void* const* d_in, const int* in_sizes, int n_in,
                              void* d_out, int out_size, void* d_ws, size_t ws_size,
                              hipStream_t stream) {
    const float* x  = (const float*)d_in[0];
    const int*   ei = (const int*)d_in[1];
    const float* W0 = (const float*)d_in[2];
    const float* b0 = (const float*)d_in[3];
    const float* W1 = (const float*)d_in[4];
    const float* b1 = (const float*)d_in[5];
    const float* W2 = (const float*)d_in[6];
    const float* b2 = (const float*)d_in[7];
    int N = in_sizes[0] / 128;
    int E = in_sizes[1] / 2;
    float* out = (float*)d_out;

    char* ws = (char*)d_ws;
    size_t off = 0;
    auto alloc = [&](size_t bytes) -> void* {
        void* p = ws + off;
        off = (off + bytes + 255) & ~(size_t)255;
        return p;
    };
    float* tA      = (float*)alloc((size_t)N * 128 * 4);
    float* tB      = (float*)alloc((size_t)N * 128 * 4);
    float* t2      = (float*)alloc((size_t)N * 16 * 4);
    int*   cnt     = (int*)alloc((size_t)N * 4);
    int*   offs    = (int*)alloc((size_t)(N + 1) * 4);
    int*   cursor  = (int*)alloc((size_t)N * 4);
    int*   blksum  = (int*)alloc(64 * 4);
    float* dis     = (float*)alloc((size_t)N * 4);
    int*   csr_col = (int*)alloc((size_t)E * 4);

    hipMemsetAsync(cnt, 0, (size_t)N * 4, stream);

    int nb = (N + 1023) / 1024;   // 49 for N=50000 (must be <= 64)
    count_kernel<<<(E + 255) / 256, 256, 0, stream>>>(ei, cnt, E);
    dis_kernel<<<(N + 255) / 256, 256, 0, stream>>>(cnt, dis, N);
    scan1_kernel<<<nb, 256, 0, stream>>>(cnt, offs, blksum, N);
    scan2_kernel<<<1, 64, 0, stream>>>(blksum, nb);
    scan3_kernel<<<(N + 255) / 256, 256, 0, stream>>>(offs, cursor, blksum, N, E);
    fill_kernel<<<(E + 255) / 256, 256, 0, stream>>>(ei, E, cursor, csr_col);

    int gemm_blocks = (N + 63) / 64;
    int agg_blocks  = (N + 3) / 4;

    gemm_nk128<<<gemm_blocks, 256, 0, stream>>>(x, W0, tA, N);
    agg128_kernel<<<agg_blocks, 256, 0, stream>>>(tA, csr_col, offs, dis, b0, tB, N, 1);
    gemm_nk128<<<gemm_blocks, 256, 0, stream>>>(tB, W1, tA, N);
    agg128_kernel<<<agg_blocks, 256, 0, stream>>>(tA, csr_col, offs, dis, b1, tB, N, 1);
    gemm_nk16<<<(N + 31) / 32, 256, 0, stream>>>(tB, W2, t2, N);
    agg16_ls_kernel<<<(int)(((size_t)N * 16 + 255) / 256), 256, 0, stream>>>(
        t2, csr_col, offs, dis, b2, out, N);
}